// Round 7
// baseline (393.151 us; speedup 1.0000x reference)
//
#include <hip/hip_runtime.h>
#include <hip/hip_fp16.h>
#include <math.h>

#define N_NODES 100000
#define D_DIM   64
#define N_EDGES 1600000
#define P_L 0.5f
#define P_H 0.5f

#define NPB   32                       // nodes per bucket (exact: 32*3125=100000)
#define NB    3125                     // number of buckets
#define TILE  8192                     // edges per partition tile
#define NT    ((N_EDGES + TILE - 1) / TILE)   // 196 tiles
#define CAP   1024                     // per-bucket record capacity (mean 512, +22 sigma)
#define ZS    132                      // z row stride (16B-aligned rows, bank-spread)

typedef unsigned int uint;
typedef unsigned short ushort_t;

__device__ inline ushort_t f2bf(float f) {
    uint u = __float_as_uint(f);
    uint r = (u + 0x7fffu + ((u >> 16) & 1u)) >> 16;
    return (ushort_t)r;
}
__device__ inline float bf2f(uint u) { return __uint_as_float(u << 16); }

// fast tanh for x >= 0
__device__ inline float tanh_pos(float x) {
    return 1.f - 2.f / (__expf(2.f * x) + 1.f);
}

// ---------------------------------------------------------------------------
// K1: per-node gate projections + h -> bf16. One wave per node.
// ---------------------------------------------------------------------------
__global__ __launch_bounds__(256) void node_gates_kernel(
    const float* __restrict__ h, const float* __restrict__ dvec,
    const float* __restrict__ Wl, const float* __restrict__ Wh,
    ushort_t* __restrict__ hbf,
    float4* __restrict__ gdst4, float4* __restrict__ gsrc4)
{
    int tid = threadIdx.x;
    int node = blockIdx.x * 4 + (tid >> 6);
    if (node >= N_NODES) return;
    int lane = tid & 63;

    float hv = h[(size_t)node * 64 + lane];
    hbf[(size_t)node * 64 + lane] = f2bf(hv);

    float pld = hv * Wl[lane];
    float pls = hv * Wl[64 + lane];
    float phd = hv * Wh[lane];
    float phs = hv * Wh[64 + lane];
    #pragma unroll
    for (int m = 32; m >= 1; m >>= 1) {
        pld += __shfl_xor(pld, m);
        pls += __shfl_xor(pls, m);
        phd += __shfl_xor(phd, m);
        phs += __shfl_xor(phs, m);
    }
    if (lane == 0) {
        float d = dvec[node];
        gdst4[node] = make_float4(pld, phd, d, 0.f);
        gsrc4[node] = make_float4(pls, phs, d, 0.f);
    }
}

// ---------------------------------------------------------------------------
// K2: per-tile bucket histogram (int LDS atomics) -> T[tile][bucket]
// ---------------------------------------------------------------------------
__global__ __launch_bounds__(1024) void bucket_hist_kernel(const int* __restrict__ dst,
                                                           int* __restrict__ T) {
    __shared__ int hist[NB];
    int tid = threadIdx.x;
    for (int i = tid; i < NB; i += 1024) hist[i] = 0;
    __syncthreads();
    int base = blockIdx.x * TILE;
    #pragma unroll
    for (int j = 0; j < TILE / 1024; ++j) {
        int e = base + j * 1024 + tid;
        if (e < N_EDGES) atomicAdd(&hist[dst[e] >> 5], 1);
    }
    __syncthreads();
    int* row = T + (size_t)blockIdx.x * NB;
    for (int i = tid; i < NB; i += 1024) row[i] = hist[i];
}

// ---------------------------------------------------------------------------
// K3a: column scan of T over tiles; totG[b] = column total.
// ---------------------------------------------------------------------------
__global__ __launch_bounds__(1024) void scanA_kernel(int* __restrict__ T,
                                                     int* __restrict__ totG) {
    int b = blockIdx.x * 1024 + threadIdx.x;
    if (b >= NB) return;
    int run = 0;
    for (int w = 0; w < NT; ++w) {
        int idx = w * NB + b;
        int v = T[idx];
        T[idx] = run;
        run += v;
    }
    totG[b] = run;
}

// ---------------------------------------------------------------------------
// K3b: exclusive scan of totG[NB] -> baseG, bucketoffs. One block.
// Also performs the Wr transpose (fused; saves a dispatch).
// ---------------------------------------------------------------------------
__global__ __launch_bounds__(1024) void scanB_kernel(const int* __restrict__ totG,
                                                     int* __restrict__ baseG,
                                                     int* __restrict__ bucketoffs,
                                                     const float* __restrict__ Wr,
                                                     float* __restrict__ wrt) {
    int tid = threadIdx.x;
    // fused transpose: wrt[k][c] = Wr[c][k]
    for (int idx = tid; idx < 64 * 128; idx += 1024) {
        int c = idx >> 7;
        int k = idx & 127;
        wrt[k * 64 + c] = Wr[idx];
    }

    __shared__ int scan_lds[1024];
    int a[4];
    int s = 0;
    #pragma unroll
    for (int i = 0; i < 4; ++i) {
        int b = tid * 4 + i;
        a[i] = (b < NB) ? totG[b] : 0;
        s += a[i];
    }
    scan_lds[tid] = s;
    __syncthreads();
    for (int d = 1; d < 1024; d <<= 1) {
        int v = (tid >= d) ? scan_lds[tid - d] : 0;
        __syncthreads();
        scan_lds[tid] += v;
        __syncthreads();
    }
    int excl = scan_lds[tid] - s;
    int total = scan_lds[1023];
    #pragma unroll
    for (int i = 0; i < 4; ++i) {
        int b = tid * 4 + i;
        if (b < NB) { baseG[b] = excl; bucketoffs[b] = excl; }
        excl += a[i];
    }
    if (tid == 0) bucketoffs[NB] = total;
}

// ---------------------------------------------------------------------------
// K4: place edges into bucket-partitioned ebuf. LDS int cursors only.
// Record: (src | dstLocal<<17, half el | half eh << 16).
// ---------------------------------------------------------------------------
__global__ __launch_bounds__(1024) void place_kernel(
    const int* __restrict__ src, const int* __restrict__ dst,
    const int* __restrict__ T, const int* __restrict__ baseG,
    const float4* __restrict__ gdst4, const float4* __restrict__ gsrc4,
    const float* __restrict__ bl, const float* __restrict__ bh,
    uint2* __restrict__ ebuf)
{
    __shared__ int cur[NB];
    int tid = threadIdx.x;
    const int* row = T + (size_t)blockIdx.x * NB;
    for (int i = tid; i < NB; i += 1024) cur[i] = row[i] + baseG[i];
    __syncthreads();

    float bl0 = bl[0], bh0 = bh[0];
    int base = blockIdx.x * TILE;
    #pragma unroll
    for (int j = 0; j < TILE / 1024; ++j) {
        int e = base + j * 1024 + tid;
        if (e >= N_EDGES) continue;
        int t = dst[e];
        int s = src[e];
        float4 gt = gdst4[t];
        float4 gs = gsrc4[s];
        float xl = gt.x + gs.x + bl0;
        float xh = gt.y + gs.y + bh0;
        float ll = xl > 0.f ? xl : -P_L * xl;   // leaky, always >= 0
        float hh = xh > 0.f ? xh : -P_H * xh;
        float dd = gt.z * gs.z;
        float el =  tanh_pos(ll) * dd;
        float eh = -tanh_pos(hh) * dd;
        uint ge = (uint)__half_as_ushort(__float2half_rn(el))
                | ((uint)__half_as_ushort(__float2half_rn(eh)) << 16);
        int b  = t >> 5;
        uint dl = (uint)(t & 31);
        int pos = atomicAdd(&cur[b], 1);        // int LDS atomic
        ebuf[pos] = make_uint2((uint)s | (dl << 17), ge);
    }
}

// ---------------------------------------------------------------------------
// K5: per-bucket accumulate + fused Wr transform.
// Phase 1-3: counting sort of records by dst-local id (int atomics only).
// Phase 4: 32 subgroups of 8 lanes; EVEN record partition across subgroups;
//          8 records per chunk via lane-parallel srec read + shfl broadcast
//          -> 8 concurrent 16B hbf gathers; VGPR accumulation; fp32 LDS
//          atomics only at node-run boundaries (~2 per subgroup).
// Phase 5: fused out = z . wrt + br.
// ---------------------------------------------------------------------------
__global__ __launch_bounds__(256) void accum_final_kernel(
    const int* __restrict__ bucketoffs, const uint2* __restrict__ ebuf,
    const ushort_t* __restrict__ hbf, const float* __restrict__ wrt,
    const float* __restrict__ br, float* __restrict__ out)
{
    __shared__ float z[NPB * ZS];
    __shared__ uint2 srec[CAP];
    __shared__ int ncount[NPB];
    __shared__ int nbase[NPB];
    __shared__ int ncur[NPB];

    int tid = threadIdx.x;
    int bk = blockIdx.x;
    int beg = bucketoffs[bk];
    int end = bucketoffs[bk + 1];
    int cnt = end - beg;
    if (cnt > CAP) cnt = CAP;    // statistically impossible (mean 512, +22 sigma)

    for (int i = tid; i < NPB * ZS; i += 256) z[i] = 0.f;
    if (tid < NPB) ncount[tid] = 0;
    __syncthreads();

    // phase 1: histogram by dst-local
    for (int i = tid; i < cnt; i += 256) {
        uint2 r = ebuf[beg + i];
        atomicAdd(&ncount[(r.x >> 17) & 31], 1);
    }
    __syncthreads();

    // phase 2: exclusive scan of 32 counts (lanes 0..31 of wave 0)
    if (tid < 32) {
        int v = ncount[tid];
        int p = v;
        #pragma unroll
        for (int d = 1; d < 32; d <<= 1) {
            int x = __shfl_up(p, d);
            if (tid >= d) p += x;
        }
        nbase[tid] = p - v;
        ncur[tid]  = p - v;
    }
    __syncthreads();

    // phase 3: counting-sort scatter into LDS
    for (int i = tid; i < cnt; i += 256) {
        uint2 r = ebuf[beg + i];
        int dl = (r.x >> 17) & 31;
        int slot = atomicAdd(&ncur[dl], 1);
        srec[slot] = r;
    }
    __syncthreads();

    // phase 4: even partition over 32 subgroups of 8 lanes
    int sg = tid >> 3;            // 0..31
    int l8 = tid & 7;             // dim slice [l8*8, l8*8+8)
    int r0 = (cnt * sg) >> 5;
    int r1 = (cnt * (sg + 1)) >> 5;

    float acc[16];
    #pragma unroll
    for (int j = 0; j < 16; ++j) acc[j] = 0.f;
    int curdl = -1;

    for (int base = r0; base < r1; base += 8) {
        int m = r1 - base; if (m > 8) m = 8;
        uint2 myrec = srec[base + (l8 < m ? l8 : m - 1)];
        uint ax[8], ay[8];
        #pragma unroll
        for (int j = 0; j < 8; ++j) {
            ax[j] = __shfl(myrec.x, j, 8);
            ay[j] = __shfl(myrec.y, j, 8);
        }
        uint4 hv[8];
        #pragma unroll
        for (int j = 0; j < 8; ++j) {
            int s = (j < m) ? (int)(ax[j] & 0x1FFFF) : 0;
            hv[j] = *(const uint4*)(hbf + (size_t)s * 64 + l8 * 8);
        }
        #pragma unroll
        for (int j = 0; j < 8; ++j) {
            if (j >= m) break;
            int dl = (int)((ax[j] >> 17) & 31);
            if (dl != curdl) {
                if (curdl >= 0) {
                    float* zp = &z[curdl * ZS + l8 * 8];
                    #pragma unroll
                    for (int c = 0; c < 8; ++c) atomicAdd(zp + c, acc[c]);
                    #pragma unroll
                    for (int c = 0; c < 8; ++c) atomicAdd(zp + 64 + c, acc[8 + c]);
                }
                curdl = dl;
                #pragma unroll
                for (int c = 0; c < 16; ++c) acc[c] = 0.f;
            }
            float el = __half2float(__ushort_as_half((unsigned short)(ay[j] & 0xffffu)));
            float eh = __half2float(__ushort_as_half((unsigned short)(ay[j] >> 16)));
            float f0 = __uint_as_float(hv[j].x << 16);
            float f1 = __uint_as_float(hv[j].x & 0xffff0000u);
            float f2 = __uint_as_float(hv[j].y << 16);
            float f3 = __uint_as_float(hv[j].y & 0xffff0000u);
            float f4 = __uint_as_float(hv[j].z << 16);
            float f5 = __uint_as_float(hv[j].z & 0xffff0000u);
            float f6 = __uint_as_float(hv[j].w << 16);
            float f7 = __uint_as_float(hv[j].w & 0xffff0000u);
            acc[0]  += el * f0; acc[1]  += el * f1; acc[2]  += el * f2; acc[3]  += el * f3;
            acc[4]  += el * f4; acc[5]  += el * f5; acc[6]  += el * f6; acc[7]  += el * f7;
            acc[8]  += eh * f0; acc[9]  += eh * f1; acc[10] += eh * f2; acc[11] += eh * f3;
            acc[12] += eh * f4; acc[13] += eh * f5; acc[14] += eh * f6; acc[15] += eh * f7;
        }
    }
    if (curdl >= 0) {
        float* zp = &z[curdl * ZS + l8 * 8];
        #pragma unroll
        for (int c = 0; c < 8; ++c) atomicAdd(zp + c, acc[c]);
        #pragma unroll
        for (int c = 0; c < 8; ++c) atomicAdd(zp + 64 + c, acc[8 + c]);
    }
    __syncthreads();

    // phase 5: fused final transform out[n] = z[n] . wrt + br
    int node = tid >> 3;          // 0..31
    int g = tid & 7;              // 8-col group
    float facc[8];
    #pragma unroll
    for (int j = 0; j < 8; ++j) facc[j] = 0.f;
    const float* zrow = z + node * ZS;
    #pragma unroll 4
    for (int kk = 0; kk < 128; ++kk) {
        float zv = zrow[kk];                      // 8-lane same-addr broadcast
        const float* w = wrt + kk * 64 + g * 8;
        float4 w0 = *(const float4*)(w);
        float4 w1 = *(const float4*)(w + 4);
        facc[0] += zv * w0.x; facc[1] += zv * w0.y; facc[2] += zv * w0.z; facc[3] += zv * w0.w;
        facc[4] += zv * w1.x; facc[5] += zv * w1.y; facc[6] += zv * w1.z; facc[7] += zv * w1.w;
    }
    int n = bk * NPB + node;
    float* op = out + (size_t)n * 64 + g * 8;
    const float* bp = br + g * 8;
    *(float4*)(op)     = make_float4(facc[0] + bp[0], facc[1] + bp[1], facc[2] + bp[2], facc[3] + bp[3]);
    *(float4*)(op + 4) = make_float4(facc[4] + bp[4], facc[5] + bp[5], facc[6] + bp[6], facc[7] + bp[7]);
}

// ---------------------------------------------------------------------------
extern "C" void kernel_launch(void* const* d_in, const int* in_sizes, int n_in,
                              void* d_out, int out_size, void* d_ws, size_t ws_size,
                              hipStream_t stream) {
    const float* h    = (const float*)d_in[0];
    const float* dvec = (const float*)d_in[1];
    const int*   src  = (const int*)  d_in[2];
    const int*   dst  = (const int*)  d_in[3];
    const float* Wl   = (const float*)d_in[4];
    const float* bl   = (const float*)d_in[5];
    const float* Wh   = (const float*)d_in[6];
    const float* bh   = (const float*)d_in[7];
    const float* Wr   = (const float*)d_in[8];
    const float* br   = (const float*)d_in[9];
    float* out = (float*)d_out;

    char* ws = (char*)d_ws;
    size_t off = 0;
    auto alloc = [&](size_t bytes) { char* p = ws + off; off += (bytes + 255) & ~size_t(255); return p; };

    ushort_t* hbf       = (ushort_t*)alloc((size_t)N_NODES * 64 * 2);     // 12.8 MB
    float4*   gdst4     = (float4*)  alloc((size_t)N_NODES * 16);         // 1.6 MB
    float4*   gsrc4     = (float4*)  alloc((size_t)N_NODES * 16);         // 1.6 MB
    float*    wrt       = (float*)   alloc(64 * 128 * 4);                 // 32 KB
    int*      T         = (int*)     alloc((size_t)NT * NB * 4);          // 2.45 MB
    int*      totG      = (int*)     alloc((size_t)NB * 4);
    int*      baseG     = (int*)     alloc((size_t)NB * 4);
    int*      bucketoffs= (int*)     alloc((size_t)(NB + 1) * 4);
    uint2*    ebuf      = (uint2*)   alloc((size_t)N_EDGES * 8);          // 12.8 MB

    node_gates_kernel<<<(N_NODES + 3) / 4, 256, 0, stream>>>(h, dvec, Wl, Wh, hbf, gdst4, gsrc4);
    bucket_hist_kernel<<<NT, 1024, 0, stream>>>(dst, T);
    scanA_kernel<<<(NB + 1023) / 1024, 1024, 0, stream>>>(T, totG);
    scanB_kernel<<<1, 1024, 0, stream>>>(totG, baseG, bucketoffs, Wr, wrt);
    place_kernel<<<NT, 1024, 0, stream>>>(src, dst, T, baseG, gdst4, gsrc4, bl, bh, ebuf);
    accum_final_kernel<<<NB, 256, 0, stream>>>(bucketoffs, ebuf, hbf, wrt, br, out);
}

// Round 8
// 387.193 us; speedup vs baseline: 1.0154x; 1.0154x over previous
//
#include <hip/hip_runtime.h>
#include <hip/hip_fp16.h>
#include <math.h>

#define N_NODES 100000
#define D_DIM   64
#define N_EDGES 1600000
#define P_L 0.5f
#define P_H 0.5f

#define NPB   32                       // nodes per bucket (exact: 32*3125=100000)
#define NB    3125                     // number of buckets
#define TILE  8192                     // edges per partition tile
#define NT    ((N_EDGES + TILE - 1) / TILE)   // 196 tiles
#define CAP   768                      // per-bucket record capacity (mean 512, sigma 22.6 -> +11 sigma)
#define ZS    132                      // z row stride (16B-aligned rows, bank-spread)

typedef unsigned int uint;
typedef unsigned short ushort_t;

__device__ inline ushort_t f2bf(float f) {
    uint u = __float_as_uint(f);
    uint r = (u + 0x7fffu + ((u >> 16) & 1u)) >> 16;
    return (ushort_t)r;
}
__device__ inline float bf2f(uint u) { return __uint_as_float(u << 16); }

// fast tanh for x >= 0
__device__ inline float tanh_pos(float x) {
    return 1.f - 2.f / (__expf(2.f * x) + 1.f);
}

// ---------------------------------------------------------------------------
// K1: per-node gate projections + h -> bf16. One wave per node.
// ---------------------------------------------------------------------------
__global__ __launch_bounds__(256) void node_gates_kernel(
    const float* __restrict__ h, const float* __restrict__ dvec,
    const float* __restrict__ Wl, const float* __restrict__ Wh,
    ushort_t* __restrict__ hbf,
    float4* __restrict__ gdst4, float4* __restrict__ gsrc4)
{
    int tid = threadIdx.x;
    int node = blockIdx.x * 4 + (tid >> 6);
    if (node >= N_NODES) return;
    int lane = tid & 63;

    float hv = h[(size_t)node * 64 + lane];
    hbf[(size_t)node * 64 + lane] = f2bf(hv);

    float pld = hv * Wl[lane];
    float pls = hv * Wl[64 + lane];
    float phd = hv * Wh[lane];
    float phs = hv * Wh[64 + lane];
    #pragma unroll
    for (int m = 32; m >= 1; m >>= 1) {
        pld += __shfl_xor(pld, m);
        pls += __shfl_xor(pls, m);
        phd += __shfl_xor(phd, m);
        phs += __shfl_xor(phs, m);
    }
    if (lane == 0) {
        float d = dvec[node];
        gdst4[node] = make_float4(pld, phd, d, 0.f);
        gsrc4[node] = make_float4(pls, phs, d, 0.f);
    }
}

// ---------------------------------------------------------------------------
// K2: per-tile bucket histogram (int LDS atomics) -> T[bucket][tile]
// (transposed layout so scanA reads are sequential per thread)
// ---------------------------------------------------------------------------
__global__ __launch_bounds__(1024) void bucket_hist_kernel(const int* __restrict__ dst,
                                                           int* __restrict__ T) {
    __shared__ int hist[NB];
    int tid = threadIdx.x;
    for (int i = tid; i < NB; i += 1024) hist[i] = 0;
    __syncthreads();
    int base = blockIdx.x * TILE;
    #pragma unroll
    for (int j = 0; j < TILE / 1024; ++j) {
        int e = base + j * 1024 + tid;
        if (e < N_EDGES) atomicAdd(&hist[dst[e] >> 5], 1);
    }
    __syncthreads();
    int w = blockIdx.x;
    for (int i = tid; i < NB; i += 1024) T[(size_t)i * NT + w] = hist[i];
}

// ---------------------------------------------------------------------------
// K3a: per-bucket scan over tiles (T[b][w] contiguous); totG[b] = total.
// ---------------------------------------------------------------------------
__global__ __launch_bounds__(1024) void scanA_kernel(int* __restrict__ T,
                                                     int* __restrict__ totG) {
    int b = blockIdx.x * 1024 + threadIdx.x;
    if (b >= NB) return;
    int* row = T + (size_t)b * NT;
    int run = 0;
    for (int w = 0; w < NT; ++w) {
        int v = row[w];
        row[w] = run;
        run += v;
    }
    totG[b] = run;
}

// ---------------------------------------------------------------------------
// K3b: exclusive scan of totG[NB] -> baseG, bucketoffs. One block.
// Also performs the Wr transpose (fused; saves a dispatch).
// ---------------------------------------------------------------------------
__global__ __launch_bounds__(1024) void scanB_kernel(const int* __restrict__ totG,
                                                     int* __restrict__ baseG,
                                                     int* __restrict__ bucketoffs,
                                                     const float* __restrict__ Wr,
                                                     float* __restrict__ wrt) {
    int tid = threadIdx.x;
    // fused transpose: wrt[k][c] = Wr[c][k]
    for (int idx = tid; idx < 64 * 128; idx += 1024) {
        int c = idx >> 7;
        int k = idx & 127;
        wrt[k * 64 + c] = Wr[idx];
    }

    __shared__ int scan_lds[1024];
    int a[4];
    int s = 0;
    #pragma unroll
    for (int i = 0; i < 4; ++i) {
        int b = tid * 4 + i;
        a[i] = (b < NB) ? totG[b] : 0;
        s += a[i];
    }
    scan_lds[tid] = s;
    __syncthreads();
    for (int d = 1; d < 1024; d <<= 1) {
        int v = (tid >= d) ? scan_lds[tid - d] : 0;
        __syncthreads();
        scan_lds[tid] += v;
        __syncthreads();
    }
    int excl = scan_lds[tid] - s;
    int total = scan_lds[1023];
    #pragma unroll
    for (int i = 0; i < 4; ++i) {
        int b = tid * 4 + i;
        if (b < NB) { baseG[b] = excl; bucketoffs[b] = excl; }
        excl += a[i];
    }
    if (tid == 0) bucketoffs[NB] = total;
}

// ---------------------------------------------------------------------------
// K4: place edges into bucket-partitioned ebuf. LDS int cursors only.
// Record: (src | dstLocal<<17, half el | half eh << 16).
// ---------------------------------------------------------------------------
__global__ __launch_bounds__(1024) void place_kernel(
    const int* __restrict__ src, const int* __restrict__ dst,
    const int* __restrict__ T, const int* __restrict__ baseG,
    const float4* __restrict__ gdst4, const float4* __restrict__ gsrc4,
    const float* __restrict__ bl, const float* __restrict__ bh,
    uint2* __restrict__ ebuf)
{
    __shared__ int cur[NB];
    int tid = threadIdx.x;
    int w = blockIdx.x;
    for (int i = tid; i < NB; i += 1024) cur[i] = T[(size_t)i * NT + w] + baseG[i];
    __syncthreads();

    float bl0 = bl[0], bh0 = bh[0];
    int base = w * TILE;
    #pragma unroll
    for (int j = 0; j < TILE / 1024; ++j) {
        int e = base + j * 1024 + tid;
        if (e >= N_EDGES) continue;
        int t = dst[e];
        int s = src[e];
        float4 gt = gdst4[t];
        float4 gs = gsrc4[s];
        float xl = gt.x + gs.x + bl0;
        float xh = gt.y + gs.y + bh0;
        float ll = xl > 0.f ? xl : -P_L * xl;   // leaky, always >= 0
        float hh = xh > 0.f ? xh : -P_H * xh;
        float dd = gt.z * gs.z;
        float el =  tanh_pos(ll) * dd;
        float eh = -tanh_pos(hh) * dd;
        uint ge = (uint)__half_as_ushort(__float2half_rn(el))
                | ((uint)__half_as_ushort(__float2half_rn(eh)) << 16);
        int b  = t >> 5;
        uint dl = (uint)(t & 31);
        int pos = atomicAdd(&cur[b], 1);        // int LDS atomic
        ebuf[pos] = make_uint2((uint)s | (dl << 17), ge);
    }
}

// ---------------------------------------------------------------------------
// K5: per-bucket accumulate + fused Wr transform.
// Phase 1-3: counting sort of records by dst-local id (int atomics only).
// Phase 4: 32 subgroups of 8 lanes; subgroup sg owns node sg (records
//          contiguous after the sort). Lane owns 8 dims -> one 16B hbf load
//          per record; unroll-4 independent chains; branch-free; VGPR acc;
//          plain z stores (no atomics -- single owner per node).
// Phase 5: fused out = z . wrt + br.
// ---------------------------------------------------------------------------
__global__ __launch_bounds__(256) void accum_final_kernel(
    const int* __restrict__ bucketoffs, const uint2* __restrict__ ebuf,
    const ushort_t* __restrict__ hbf, const float* __restrict__ wrt,
    const float* __restrict__ br, float* __restrict__ out)
{
    __shared__ float z[NPB * ZS];
    __shared__ uint2 srec[CAP];
    __shared__ int ncount[NPB];
    __shared__ int nbase[NPB];
    __shared__ int ncur[NPB];

    int tid = threadIdx.x;
    int bk = blockIdx.x;
    int beg = bucketoffs[bk];
    int end = bucketoffs[bk + 1];
    int cnt = end - beg;
    if (cnt > CAP) cnt = CAP;    // statistically impossible (mean 512, +11 sigma)

    if (tid < NPB) ncount[tid] = 0;
    __syncthreads();

    // phase 1: histogram by dst-local
    for (int i = tid; i < cnt; i += 256) {
        uint2 r = ebuf[beg + i];
        atomicAdd(&ncount[(r.x >> 17) & 31], 1);
    }
    __syncthreads();

    // phase 2: exclusive scan of 32 counts (lanes 0..31 of wave 0)
    if (tid < 32) {
        int v = ncount[tid];
        int p = v;
        #pragma unroll
        for (int d = 1; d < 32; d <<= 1) {
            int x = __shfl_up(p, d);
            if (tid >= d) p += x;
        }
        nbase[tid] = p - v;
        ncur[tid]  = p - v;
    }
    __syncthreads();

    // phase 3: counting-sort scatter into LDS
    for (int i = tid; i < cnt; i += 256) {
        uint2 r = ebuf[beg + i];
        int dl = (r.x >> 17) & 31;
        int slot = atomicAdd(&ncur[dl], 1);
        srec[slot] = r;
    }
    __syncthreads();

    // phase 4: subgroup sg (8 lanes) owns node sg; lane owns dims [l8*8, l8*8+8)
    int sg = tid >> 3;            // 0..31
    int l8 = tid & 7;
    int rbeg = nbase[sg];
    int rend = ncur[sg];          // nbase + count

    float acc[16];
    #pragma unroll
    for (int j = 0; j < 16; ++j) acc[j] = 0.f;

    int k = rbeg;
    for (; k + 3 < rend; k += 4) {
        uint2 r0 = srec[k];       // same addr across 8 lanes: LDS broadcast
        uint2 r1 = srec[k + 1];
        uint2 r2 = srec[k + 2];
        uint2 r3 = srec[k + 3];
        uint4 h0 = *(const uint4*)(hbf + (size_t)(r0.x & 0x1FFFF) * 64 + l8 * 8);
        uint4 h1 = *(const uint4*)(hbf + (size_t)(r1.x & 0x1FFFF) * 64 + l8 * 8);
        uint4 h2 = *(const uint4*)(hbf + (size_t)(r2.x & 0x1FFFF) * 64 + l8 * 8);
        uint4 h3 = *(const uint4*)(hbf + (size_t)(r3.x & 0x1FFFF) * 64 + l8 * 8);

        #pragma unroll
        for (int u = 0; u < 4; ++u) {
            uint gy = (u == 0) ? r0.y : (u == 1) ? r1.y : (u == 2) ? r2.y : r3.y;
            uint4 hv = (u == 0) ? h0 : (u == 1) ? h1 : (u == 2) ? h2 : h3;
            float el = __half2float(__ushort_as_half((unsigned short)(gy & 0xffffu)));
            float eh = __half2float(__ushort_as_half((unsigned short)(gy >> 16)));
            float f0 = __uint_as_float(hv.x << 16);
            float f1 = __uint_as_float(hv.x & 0xffff0000u);
            float f2 = __uint_as_float(hv.y << 16);
            float f3 = __uint_as_float(hv.y & 0xffff0000u);
            float f4 = __uint_as_float(hv.z << 16);
            float f5 = __uint_as_float(hv.z & 0xffff0000u);
            float f6 = __uint_as_float(hv.w << 16);
            float f7 = __uint_as_float(hv.w & 0xffff0000u);
            acc[0]  += el * f0; acc[1]  += el * f1; acc[2]  += el * f2; acc[3]  += el * f3;
            acc[4]  += el * f4; acc[5]  += el * f5; acc[6]  += el * f6; acc[7]  += el * f7;
            acc[8]  += eh * f0; acc[9]  += eh * f1; acc[10] += eh * f2; acc[11] += eh * f3;
            acc[12] += eh * f4; acc[13] += eh * f5; acc[14] += eh * f6; acc[15] += eh * f7;
        }
    }
    for (; k < rend; ++k) {
        uint2 r0 = srec[k];
        uint4 hv = *(const uint4*)(hbf + (size_t)(r0.x & 0x1FFFF) * 64 + l8 * 8);
        float el = __half2float(__ushort_as_half((unsigned short)(r0.y & 0xffffu)));
        float eh = __half2float(__ushort_as_half((unsigned short)(r0.y >> 16)));
        float f0 = __uint_as_float(hv.x << 16);
        float f1 = __uint_as_float(hv.x & 0xffff0000u);
        float f2 = __uint_as_float(hv.y << 16);
        float f3 = __uint_as_float(hv.y & 0xffff0000u);
        float f4 = __uint_as_float(hv.z << 16);
        float f5 = __uint_as_float(hv.z & 0xffff0000u);
        float f6 = __uint_as_float(hv.w << 16);
        float f7 = __uint_as_float(hv.w & 0xffff0000u);
        acc[0]  += el * f0; acc[1]  += el * f1; acc[2]  += el * f2; acc[3]  += el * f3;
        acc[4]  += el * f4; acc[5]  += el * f5; acc[6]  += el * f6; acc[7]  += el * f7;
        acc[8]  += eh * f0; acc[9]  += eh * f1; acc[10] += eh * f2; acc[11] += eh * f3;
        acc[12] += eh * f4; acc[13] += eh * f5; acc[14] += eh * f6; acc[15] += eh * f7;
    }

    // plain z stores: each (node, dim) has exactly one owner lane
    {
        float* zp = &z[sg * ZS + l8 * 8];
        *(float4*)(zp + 0)  = make_float4(acc[0],  acc[1],  acc[2],  acc[3]);
        *(float4*)(zp + 4)  = make_float4(acc[4],  acc[5],  acc[6],  acc[7]);
        *(float4*)(zp + 64) = make_float4(acc[8],  acc[9],  acc[10], acc[11]);
        *(float4*)(zp + 68) = make_float4(acc[12], acc[13], acc[14], acc[15]);
    }
    __syncthreads();

    // phase 5: fused final transform out[n] = z[n] . wrt + br
    int node = tid >> 3;          // 0..31
    int g = tid & 7;              // 8-col group
    float facc[8];
    #pragma unroll
    for (int j = 0; j < 8; ++j) facc[j] = 0.f;
    const float* zrow = z + node * ZS;
    #pragma unroll 4
    for (int kk = 0; kk < 128; ++kk) {
        float zv = zrow[kk];                      // 8-lane same-addr broadcast
        const float* w = wrt + kk * 64 + g * 8;
        float4 w0 = *(const float4*)(w);
        float4 w1 = *(const float4*)(w + 4);
        facc[0] += zv * w0.x; facc[1] += zv * w0.y; facc[2] += zv * w0.z; facc[3] += zv * w0.w;
        facc[4] += zv * w1.x; facc[5] += zv * w1.y; facc[6] += zv * w1.z; facc[7] += zv * w1.w;
    }
    int n = bk * NPB + node;
    float* op = out + (size_t)n * 64 + g * 8;
    const float* bp = br + g * 8;
    *(float4*)(op)     = make_float4(facc[0] + bp[0], facc[1] + bp[1], facc[2] + bp[2], facc[3] + bp[3]);
    *(float4*)(op + 4) = make_float4(facc[4] + bp[4], facc[5] + bp[5], facc[6] + bp[6], facc[7] + bp[7]);
}

// ---------------------------------------------------------------------------
extern "C" void kernel_launch(void* const* d_in, const int* in_sizes, int n_in,
                              void* d_out, int out_size, void* d_ws, size_t ws_size,
                              hipStream_t stream) {
    const float* h    = (const float*)d_in[0];
    const float* dvec = (const float*)d_in[1];
    const int*   src  = (const int*)  d_in[2];
    const int*   dst  = (const int*)  d_in[3];
    const float* Wl   = (const float*)d_in[4];
    const float* bl   = (const float*)d_in[5];
    const float* Wh   = (const float*)d_in[6];
    const float* bh   = (const float*)d_in[7];
    const float* Wr   = (const float*)d_in[8];
    const float* br   = (const float*)d_in[9];
    float* out = (float*)d_out;

    char* ws = (char*)d_ws;
    size_t off = 0;
    auto alloc = [&](size_t bytes) { char* p = ws + off; off += (bytes + 255) & ~size_t(255); return p; };

    ushort_t* hbf       = (ushort_t*)alloc((size_t)N_NODES * 64 * 2);     // 12.8 MB
    float4*   gdst4     = (float4*)  alloc((size_t)N_NODES * 16);         // 1.6 MB
    float4*   gsrc4     = (float4*)  alloc((size_t)N_NODES * 16);         // 1.6 MB
    float*    wrt       = (float*)   alloc(64 * 128 * 4);                 // 32 KB
    int*      T         = (int*)     alloc((size_t)NB * NT * 4);          // 2.45 MB
    int*      totG      = (int*)     alloc((size_t)NB * 4);
    int*      baseG     = (int*)     alloc((size_t)NB * 4);
    int*      bucketoffs= (int*)     alloc((size_t)(NB + 1) * 4);
    uint2*    ebuf      = (uint2*)   alloc((size_t)N_EDGES * 8);          // 12.8 MB

    node_gates_kernel<<<(N_NODES + 3) / 4, 256, 0, stream>>>(h, dvec, Wl, Wh, hbf, gdst4, gsrc4);
    bucket_hist_kernel<<<NT, 1024, 0, stream>>>(dst, T);
    scanA_kernel<<<(NB + 1023) / 1024, 1024, 0, stream>>>(T, totG);
    scanB_kernel<<<1, 1024, 0, stream>>>(totG, baseG, bucketoffs, Wr, wrt);
    place_kernel<<<NT, 1024, 0, stream>>>(src, dst, T, baseG, gdst4, gsrc4, bl, bh, ebuf);
    accum_final_kernel<<<NB, 256, 0, stream>>>(bucketoffs, ebuf, hbf, wrt, br, out);
}

// Round 9
// 312.739 us; speedup vs baseline: 1.2571x; 1.2381x over previous
//
#include <hip/hip_runtime.h>
#include <hip/hip_fp16.h>
#include <math.h>

#define N_NODES 100000
#define D_DIM   64
#define N_EDGES 1600000
#define P_L 0.5f
#define P_H 0.5f

#define NPB   32                       // nodes per bucket (exact: 32*3125=100000)
#define NB    3125                     // number of buckets
#define TILE  8192                     // edges per partition tile
#define NT    ((N_EDGES + TILE - 1) / TILE)   // 196 tiles
#define CAP   768                      // per-bucket record capacity (mean 512, +11 sigma)
#define ZS    132                      // z row stride (16B-aligned rows, bank-spread)

typedef unsigned int uint;
typedef unsigned short ushort_t;

__device__ inline ushort_t f2bf(float f) {
    uint u = __float_as_uint(f);
    uint r = (u + 0x7fffu + ((u >> 16) & 1u)) >> 16;
    return (ushort_t)r;
}

// fast tanh for x >= 0
__device__ inline float tanh_pos(float x) {
    return 1.f - 2.f / (__expf(2.f * x) + 1.f);
}

// ---------------------------------------------------------------------------
// K1: per-node gate projections + h -> bf16. One wave per node.
// ---------------------------------------------------------------------------
__global__ __launch_bounds__(256) void node_gates_kernel(
    const float* __restrict__ h, const float* __restrict__ dvec,
    const float* __restrict__ Wl, const float* __restrict__ Wh,
    ushort_t* __restrict__ hbf,
    float4* __restrict__ gdst4, float4* __restrict__ gsrc4)
{
    int tid = threadIdx.x;
    int node = blockIdx.x * 4 + (tid >> 6);
    if (node >= N_NODES) return;
    int lane = tid & 63;

    float hv = h[(size_t)node * 64 + lane];
    hbf[(size_t)node * 64 + lane] = f2bf(hv);

    float pld = hv * Wl[lane];
    float pls = hv * Wl[64 + lane];
    float phd = hv * Wh[lane];
    float phs = hv * Wh[64 + lane];
    #pragma unroll
    for (int m = 32; m >= 1; m >>= 1) {
        pld += __shfl_xor(pld, m);
        pls += __shfl_xor(pls, m);
        phd += __shfl_xor(phd, m);
        phs += __shfl_xor(phs, m);
    }
    if (lane == 0) {
        float d = dvec[node];
        gdst4[node] = make_float4(pld, phd, d, 0.f);
        gsrc4[node] = make_float4(pls, phs, d, 0.f);
    }
}

// ---------------------------------------------------------------------------
// K2: per-tile bucket histogram (int LDS atomics) -> T[tile][bucket]
// (row store is lane-coalesced)
// ---------------------------------------------------------------------------
__global__ __launch_bounds__(1024) void bucket_hist_kernel(const int* __restrict__ dst,
                                                           int* __restrict__ T) {
    __shared__ int hist[NB];
    int tid = threadIdx.x;
    for (int i = tid; i < NB; i += 1024) hist[i] = 0;
    __syncthreads();
    int base = blockIdx.x * TILE;
    #pragma unroll
    for (int j = 0; j < TILE / 1024; ++j) {
        int e = base + j * 1024 + tid;
        if (e < N_EDGES) atomicAdd(&hist[dst[e] >> 5], 1);
    }
    __syncthreads();
    int* row = T + (size_t)blockIdx.x * NB;
    for (int i = tid; i < NB; i += 1024) row[i] = hist[i];
}

// ---------------------------------------------------------------------------
// K3a: column scan of T over tiles (lane-coalesced: consecutive b =
// consecutive addresses); totG[b] = column total.
// ---------------------------------------------------------------------------
__global__ __launch_bounds__(1024) void scanA_kernel(int* __restrict__ T,
                                                     int* __restrict__ totG) {
    int b = blockIdx.x * 1024 + threadIdx.x;
    if (b >= NB) return;
    int run = 0;
    for (int w = 0; w < NT; ++w) {
        int idx = w * NB + b;
        int v = T[idx];
        T[idx] = run;
        run += v;
    }
    totG[b] = run;
}

// ---------------------------------------------------------------------------
// K3b: exclusive scan of totG[NB] -> baseG, bucketoffs. One block.
// Also performs the Wr transpose (fused; saves a dispatch).
// ---------------------------------------------------------------------------
__global__ __launch_bounds__(1024) void scanB_kernel(const int* __restrict__ totG,
                                                     int* __restrict__ baseG,
                                                     int* __restrict__ bucketoffs,
                                                     const float* __restrict__ Wr,
                                                     float* __restrict__ wrt) {
    int tid = threadIdx.x;
    // fused transpose: wrt[k][c] = Wr[c][k]
    for (int idx = tid; idx < 64 * 128; idx += 1024) {
        int c = idx >> 7;
        int k = idx & 127;
        wrt[k * 64 + c] = Wr[idx];
    }

    __shared__ int scan_lds[1024];
    int a[4];
    int s = 0;
    #pragma unroll
    for (int i = 0; i < 4; ++i) {
        int b = tid * 4 + i;
        a[i] = (b < NB) ? totG[b] : 0;
        s += a[i];
    }
    scan_lds[tid] = s;
    __syncthreads();
    for (int d = 1; d < 1024; d <<= 1) {
        int v = (tid >= d) ? scan_lds[tid - d] : 0;
        __syncthreads();
        scan_lds[tid] += v;
        __syncthreads();
    }
    int excl = scan_lds[tid] - s;
    int total = scan_lds[1023];
    #pragma unroll
    for (int i = 0; i < 4; ++i) {
        int b = tid * 4 + i;
        if (b < NB) { baseG[b] = excl; bucketoffs[b] = excl; }
        excl += a[i];
    }
    if (tid == 0) bucketoffs[NB] = total;
}

// ---------------------------------------------------------------------------
// K4: place edges into bucket-partitioned ebuf. LDS int cursors only.
// Record: (src | dstLocal<<17, half el | half eh << 16).
// ---------------------------------------------------------------------------
__global__ __launch_bounds__(1024) void place_kernel(
    const int* __restrict__ src, const int* __restrict__ dst,
    const int* __restrict__ T, const int* __restrict__ baseG,
    const float4* __restrict__ gdst4, const float4* __restrict__ gsrc4,
    const float* __restrict__ bl, const float* __restrict__ bh,
    uint2* __restrict__ ebuf)
{
    __shared__ int cur[NB];
    int tid = threadIdx.x;
    const int* row = T + (size_t)blockIdx.x * NB;
    for (int i = tid; i < NB; i += 1024) cur[i] = row[i] + baseG[i];
    __syncthreads();

    float bl0 = bl[0], bh0 = bh[0];
    int base = blockIdx.x * TILE;
    #pragma unroll
    for (int j = 0; j < TILE / 1024; ++j) {
        int e = base + j * 1024 + tid;
        if (e >= N_EDGES) continue;
        int t = dst[e];
        int s = src[e];
        float4 gt = gdst4[t];
        float4 gs = gsrc4[s];
        float xl = gt.x + gs.x + bl0;
        float xh = gt.y + gs.y + bh0;
        float ll = xl > 0.f ? xl : -P_L * xl;   // leaky, always >= 0
        float hh = xh > 0.f ? xh : -P_H * xh;
        float dd = gt.z * gs.z;
        float el =  tanh_pos(ll) * dd;
        float eh = -tanh_pos(hh) * dd;
        uint ge = (uint)__half_as_ushort(__float2half_rn(el))
                | ((uint)__half_as_ushort(__float2half_rn(eh)) << 16);
        int b  = t >> 5;
        uint dl = (uint)(t & 31);
        int pos = atomicAdd(&cur[b], 1);        // int LDS atomic
        ebuf[pos] = make_uint2((uint)s | (dl << 17), ge);
    }
}

// ---------------------------------------------------------------------------
// K5: per-bucket accumulate + fused Wr transform. 512 threads/block.
// Records loaded ONCE into VGPRs (<=2/thread); histogram + counting-sort
// scatter run from registers (single global pass over ebuf).
// Phase 4: 64 subgroups of 8 lanes; TWO subgroups per node (even/odd record
// parity) -> serial chain ~8 records; unroll-4; VGPR acc; parity-0 stores z,
// barrier, parity-1 adds in. Zero fp32 atomics.
// Phase 5: fused out = z . wrt + br (16 threads per node, 4 cols each).
// ---------------------------------------------------------------------------
__global__ __launch_bounds__(512) void accum_final_kernel(
    const int* __restrict__ bucketoffs, const uint2* __restrict__ ebuf,
    const ushort_t* __restrict__ hbf, const float* __restrict__ wrt,
    const float* __restrict__ br, float* __restrict__ out)
{
    __shared__ float z[NPB * ZS];        // 16.9 KB
    __shared__ uint2 srec[CAP];          // 6 KB
    __shared__ int ncount[NPB];
    __shared__ int nbase[NPB];
    __shared__ int ncur[NPB];

    int tid = threadIdx.x;
    int bk = blockIdx.x;
    int beg = bucketoffs[bk];
    int end = bucketoffs[bk + 1];
    int cnt = end - beg;
    if (cnt > CAP) cnt = CAP;    // statistically impossible (mean 512, +11 sigma)

    if (tid < NPB) ncount[tid] = 0;

    // single coalesced global pass: records live in VGPRs
    bool hA = tid < cnt;
    bool hB = tid + 512 < cnt;
    uint2 rA = hA ? ebuf[beg + tid] : make_uint2(0, 0);
    uint2 rB = hB ? ebuf[beg + tid + 512] : make_uint2(0, 0);
    __syncthreads();

    // phase 1: histogram by dst-local (from regs)
    if (hA) atomicAdd(&ncount[(rA.x >> 17) & 31], 1);
    if (hB) atomicAdd(&ncount[(rB.x >> 17) & 31], 1);
    __syncthreads();

    // phase 2: exclusive scan of 32 counts (lanes 0..31 of wave 0)
    if (tid < 32) {
        int v = ncount[tid];
        int p = v;
        #pragma unroll
        for (int d = 1; d < 32; d <<= 1) {
            int x = __shfl_up(p, d);
            if (tid >= d) p += x;
        }
        nbase[tid] = p - v;
        ncur[tid]  = p - v;
    }
    __syncthreads();

    // phase 3: counting-sort scatter into LDS (from regs)
    if (hA) {
        int dl = (rA.x >> 17) & 31;
        srec[atomicAdd(&ncur[dl], 1)] = rA;
    }
    if (hB) {
        int dl = (rB.x >> 17) & 31;
        srec[atomicAdd(&ncur[dl], 1)] = rB;
    }
    __syncthreads();

    // phase 4: subgroup sg (8 lanes) = node sg>>1, parity sg&1
    int sg = tid >> 3;            // 0..63
    int l8 = tid & 7;
    int node4 = sg >> 1;
    int par = sg & 1;
    int rbeg = nbase[node4];
    int rend = ncur[node4];       // nbase + count

    float acc[16];
    #pragma unroll
    for (int j = 0; j < 16; ++j) acc[j] = 0.f;

    int k = rbeg + par;
    for (; k + 6 < rend; k += 8) {
        uint2 r0 = srec[k];       // subgroup-uniform addr: LDS broadcast
        uint2 r1 = srec[k + 2];
        uint2 r2 = srec[k + 4];
        uint2 r3 = srec[k + 6];
        uint4 h0 = *(const uint4*)(hbf + (size_t)(r0.x & 0x1FFFF) * 64 + l8 * 8);
        uint4 h1 = *(const uint4*)(hbf + (size_t)(r1.x & 0x1FFFF) * 64 + l8 * 8);
        uint4 h2 = *(const uint4*)(hbf + (size_t)(r2.x & 0x1FFFF) * 64 + l8 * 8);
        uint4 h3 = *(const uint4*)(hbf + (size_t)(r3.x & 0x1FFFF) * 64 + l8 * 8);

        #pragma unroll
        for (int u = 0; u < 4; ++u) {
            uint gy = (u == 0) ? r0.y : (u == 1) ? r1.y : (u == 2) ? r2.y : r3.y;
            uint4 hv = (u == 0) ? h0 : (u == 1) ? h1 : (u == 2) ? h2 : h3;
            float el = __half2float(__ushort_as_half((unsigned short)(gy & 0xffffu)));
            float eh = __half2float(__ushort_as_half((unsigned short)(gy >> 16)));
            float f0 = __uint_as_float(hv.x << 16);
            float f1 = __uint_as_float(hv.x & 0xffff0000u);
            float f2 = __uint_as_float(hv.y << 16);
            float f3 = __uint_as_float(hv.y & 0xffff0000u);
            float f4 = __uint_as_float(hv.z << 16);
            float f5 = __uint_as_float(hv.z & 0xffff0000u);
            float f6 = __uint_as_float(hv.w << 16);
            float f7 = __uint_as_float(hv.w & 0xffff0000u);
            acc[0]  += el * f0; acc[1]  += el * f1; acc[2]  += el * f2; acc[3]  += el * f3;
            acc[4]  += el * f4; acc[5]  += el * f5; acc[6]  += el * f6; acc[7]  += el * f7;
            acc[8]  += eh * f0; acc[9]  += eh * f1; acc[10] += eh * f2; acc[11] += eh * f3;
            acc[12] += eh * f4; acc[13] += eh * f5; acc[14] += eh * f6; acc[15] += eh * f7;
        }
    }
    for (; k < rend; k += 2) {
        uint2 r0 = srec[k];
        uint4 hv = *(const uint4*)(hbf + (size_t)(r0.x & 0x1FFFF) * 64 + l8 * 8);
        float el = __half2float(__ushort_as_half((unsigned short)(r0.y & 0xffffu)));
        float eh = __half2float(__ushort_as_half((unsigned short)(r0.y >> 16)));
        float f0 = __uint_as_float(hv.x << 16);
        float f1 = __uint_as_float(hv.x & 0xffff0000u);
        float f2 = __uint_as_float(hv.y << 16);
        float f3 = __uint_as_float(hv.y & 0xffff0000u);
        float f4 = __uint_as_float(hv.z << 16);
        float f5 = __uint_as_float(hv.z & 0xffff0000u);
        float f6 = __uint_as_float(hv.w << 16);
        float f7 = __uint_as_float(hv.w & 0xffff0000u);
        acc[0]  += el * f0; acc[1]  += el * f1; acc[2]  += el * f2; acc[3]  += el * f3;
        acc[4]  += el * f4; acc[5]  += el * f5; acc[6]  += el * f6; acc[7]  += el * f7;
        acc[8]  += eh * f0; acc[9]  += eh * f1; acc[10] += eh * f2; acc[11] += eh * f3;
        acc[12] += eh * f4; acc[13] += eh * f5; acc[14] += eh * f6; acc[15] += eh * f7;
    }

    float* zp = &z[node4 * ZS + l8 * 8];
    if (par == 0) {
        *(float4*)(zp + 0)  = make_float4(acc[0],  acc[1],  acc[2],  acc[3]);
        *(float4*)(zp + 4)  = make_float4(acc[4],  acc[5],  acc[6],  acc[7]);
        *(float4*)(zp + 64) = make_float4(acc[8],  acc[9],  acc[10], acc[11]);
        *(float4*)(zp + 68) = make_float4(acc[12], acc[13], acc[14], acc[15]);
    }
    __syncthreads();
    if (par == 1) {
        float4 z0 = *(float4*)(zp + 0);
        float4 z1 = *(float4*)(zp + 4);
        float4 z2 = *(float4*)(zp + 64);
        float4 z3 = *(float4*)(zp + 68);
        *(float4*)(zp + 0)  = make_float4(z0.x + acc[0],  z0.y + acc[1],  z0.z + acc[2],  z0.w + acc[3]);
        *(float4*)(zp + 4)  = make_float4(z1.x + acc[4],  z1.y + acc[5],  z1.z + acc[6],  z1.w + acc[7]);
        *(float4*)(zp + 64) = make_float4(z2.x + acc[8],  z2.y + acc[9],  z2.z + acc[10], z2.w + acc[11]);
        *(float4*)(zp + 68) = make_float4(z3.x + acc[12], z3.y + acc[13], z3.z + acc[14], z3.w + acc[15]);
    }
    __syncthreads();

    // phase 5: fused final transform out[n] = z[n] . wrt + br
    int node = tid >> 4;          // 0..31
    int g = tid & 15;             // 4-col group
    float facc[4] = {0.f, 0.f, 0.f, 0.f};
    const float* zrow = z + node * ZS;
    #pragma unroll 4
    for (int kk = 0; kk < 128; ++kk) {
        float zv = zrow[kk];                      // 16-lane same-addr broadcast
        float4 w = *(const float4*)(wrt + kk * 64 + g * 4);
        facc[0] += zv * w.x; facc[1] += zv * w.y; facc[2] += zv * w.z; facc[3] += zv * w.w;
    }
    int n = bk * NPB + node;
    float* op = out + (size_t)n * 64 + g * 4;
    const float* bp = br + g * 4;
    *(float4*)(op) = make_float4(facc[0] + bp[0], facc[1] + bp[1], facc[2] + bp[2], facc[3] + bp[3]);
}

// ---------------------------------------------------------------------------
extern "C" void kernel_launch(void* const* d_in, const int* in_sizes, int n_in,
                              void* d_out, int out_size, void* d_ws, size_t ws_size,
                              hipStream_t stream) {
    const float* h    = (const float*)d_in[0];
    const float* dvec = (const float*)d_in[1];
    const int*   src  = (const int*)  d_in[2];
    const int*   dst  = (const int*)  d_in[3];
    const float* Wl   = (const float*)d_in[4];
    const float* bl   = (const float*)d_in[5];
    const float* Wh   = (const float*)d_in[6];
    const float* bh   = (const float*)d_in[7];
    const float* Wr   = (const float*)d_in[8];
    const float* br   = (const float*)d_in[9];
    float* out = (float*)d_out;

    char* ws = (char*)d_ws;
    size_t off = 0;
    auto alloc = [&](size_t bytes) { char* p = ws + off; off += (bytes + 255) & ~size_t(255); return p; };

    ushort_t* hbf       = (ushort_t*)alloc((size_t)N_NODES * 64 * 2);     // 12.8 MB
    float4*   gdst4     = (float4*)  alloc((size_t)N_NODES * 16);         // 1.6 MB
    float4*   gsrc4     = (float4*)  alloc((size_t)N_NODES * 16);         // 1.6 MB
    float*    wrt       = (float*)   alloc(64 * 128 * 4);                 // 32 KB
    int*      T         = (int*)     alloc((size_t)NT * NB * 4);          // 2.45 MB
    int*      totG      = (int*)     alloc((size_t)NB * 4);
    int*      baseG     = (int*)     alloc((size_t)NB * 4);
    int*      bucketoffs= (int*)     alloc((size_t)(NB + 1) * 4);
    uint2*    ebuf      = (uint2*)   alloc((size_t)N_EDGES * 8);          // 12.8 MB

    node_gates_kernel<<<(N_NODES + 3) / 4, 256, 0, stream>>>(h, dvec, Wl, Wh, hbf, gdst4, gsrc4);
    bucket_hist_kernel<<<NT, 1024, 0, stream>>>(dst, T);
    scanA_kernel<<<(NB + 1023) / 1024, 1024, 0, stream>>>(T, totG);
    scanB_kernel<<<1, 1024, 0, stream>>>(totG, baseG, bucketoffs, Wr, wrt);
    place_kernel<<<NT, 1024, 0, stream>>>(src, dst, T, baseG, gdst4, gsrc4, bl, bh, ebuf);
    accum_final_kernel<<<NB, 512, 0, stream>>>(bucketoffs, ebuf, hbf, wrt, br, out);
}